// Round 2
// baseline (57151.825 us; speedup 1.0000x reference)
//
#include <hip/hip_runtime.h>
#include <hip/hip_bf16.h>

#define TT   2048
#define NN   11
#define EE   110
#define NFD  5
#define EFD  4
#define HIDD 256
#define EEDD 32
#define DD1  256
#define G3   768

// ---------------------------------------------------------------------------
// Kernel A: time-parallel precompute. One block per timestep t.
// Computes node_proj -> edge_proj -> GAT1 -> GAT2 -> LayerNorm -> gi, evc.
// ---------------------------------------------------------------------------
__global__ __launch_bounds__(256) void precompute_kernel(
    const float* __restrict__ x, const float* __restrict__ edge_attr,
    const float* __restrict__ evs, const int* __restrict__ eidx,
    const float* __restrict__ W_np, const float* __restrict__ b_np,
    const float* __restrict__ bn_g, const float* __restrict__ bn_b,
    const float* __restrict__ We1, const float* __restrict__ be1,
    const float* __restrict__ We2, const float* __restrict__ be2,
    const float* __restrict__ Wg1, const float* __restrict__ bg1,
    const float* __restrict__ Wa1, const float* __restrict__ ba1,
    const float* __restrict__ Wg2, const float* __restrict__ bg2,
    const float* __restrict__ Wa2, const float* __restrict__ ba2,
    const float* __restrict__ ln_g, const float* __restrict__ ln_b,
    const float* __restrict__ W_ih, const float* __restrict__ b_ih,
    const float* __restrict__ Wf, const float* __restrict__ bf_,
    float* __restrict__ gi_out, float* __restrict__ evc_out)
{
    const int t   = blockIdx.x;
    const int tid = threadIdx.x;

    __shared__ __align__(16) float sh_h[NN][64];    // node proj (BN'd)
    __shared__ __align__(16) float sh_e1[EE][32];
    __shared__ __align__(16) float sh_ea[EE][16];
    __shared__ __align__(16) float sh_h1[NN][DD1];  // GAT linear out (reused)
    __shared__ __align__(16) float sh_x[NN][DD1];   // x1 then x2/x2ln (reused)
    __shared__ float sxt[NN * NFD];
    __shared__ float sev[EEDD];
    __shared__ float seat[EE * EFD];
    __shared__ float red[356];
    __shared__ float sh_s1[NN], sh_d1[NN];
    __shared__ float sh_elog[EE], sh_logit[EE], sh_alpha[EE];
    __shared__ float sh_mu[NN], sh_rs[NN];
    __shared__ float sredv[2];
    __shared__ int s_src[EE], s_dst[EE];
    __shared__ int cnt[NN], deg_start[NN + 1], e_by_dst[EE];

    // ---- stage inputs + build CSR by dst -----------------------------------
    if (tid < NN * NFD) sxt[tid] = x[(size_t)t * NN * NFD + tid];
    if (tid < EEDD)     sev[tid] = evs[(size_t)t * EEDD + tid];
    for (int i = tid; i < EE * EFD; i += 256)
        seat[i] = edge_attr[(size_t)t * EE * EFD + i];
    if (tid < EE) { s_src[tid] = eidx[tid]; s_dst[tid] = eidx[EE + tid]; }
    if (tid < NN) cnt[tid] = 0;
    __syncthreads();
    if (tid < EE) atomicAdd(&cnt[s_dst[tid]], 1);
    __syncthreads();
    if (tid == 0) {
        int a = 0;
        for (int n = 0; n < NN; n++) { deg_start[n] = a; a += cnt[n]; }
        deg_start[NN] = a;
    }
    __syncthreads();
    if (tid < NN) cnt[tid] = 0;
    __syncthreads();
    if (tid < EE) {
        int d = s_dst[tid];
        int pos = deg_start[d] + atomicAdd(&cnt[d], 1);
        e_by_dst[pos] = tid;
    }

    // ---- node_proj: relu(x@W_np+b) then eval-BatchNorm ---------------------
    // NOTE: NN*64 = 704 > 256 threads -> MUST be a grid-stride loop (round-1 bug fix)
    const float bn_inv = 1.0f / sqrtf(1.0f + 1e-5f);
    __syncthreads();
    for (int i = tid; i < NN * 64; i += 256) {
        int n = i >> 6, d = i & 63;
        float a = b_np[d];
        #pragma unroll
        for (int k = 0; k < NFD; k++) a += sxt[n * NFD + k] * W_np[k * 64 + d];
        a = fmaxf(a, 0.f);
        sh_h[n][d] = bn_g[d] * (a * bn_inv) + bn_b[d];
    }
    __syncthreads();

    // ---- edge_proj ---------------------------------------------------------
    for (int i = tid; i < EE * 32; i += 256) {
        int e = i >> 5, d = i & 31;
        float a = be1[d];
        #pragma unroll
        for (int k = 0; k < EFD; k++) a += seat[e * EFD + k] * We1[k * 32 + d];
        sh_e1[e][d] = fmaxf(a, 0.f);
    }
    __syncthreads();
    for (int i = tid; i < EE * 16; i += 256) {
        int e = i >> 4, d = i & 15;
        float a = be2[d];
        #pragma unroll
        for (int k = 0; k < 32; k++) a += sh_e1[e][k] * We2[k * 16 + d];
        sh_ea[e][d] = fmaxf(a, 0.f);
    }
    __syncthreads();

    // ======================= GAT layer 1 ====================================
    { // linear: sh_h1 = sh_h @ Wg1 + bg1   (in-dim 64)
        const int j = tid;
        float acc[NN];
        #pragma unroll
        for (int n = 0; n < NN; n++) acc[n] = bg1[j];
        for (int k = 0; k < 64; k += 4) {
            float w0 = Wg1[(k + 0) * DD1 + j], w1 = Wg1[(k + 1) * DD1 + j];
            float w2 = Wg1[(k + 2) * DD1 + j], w3 = Wg1[(k + 3) * DD1 + j];
            #pragma unroll
            for (int n = 0; n < NN; n++) {
                float4 hv = *(const float4*)&sh_h[n][k];
                acc[n] = fmaf(hv.w, w3, fmaf(hv.z, w2, fmaf(hv.y, w1, fmaf(hv.x, w0, acc[n]))));
            }
        }
        #pragma unroll
        for (int n = 0; n < NN; n++) sh_h1[n][j] = acc[n];
    }
    __syncthreads();
    // edge scores: logit[e] = s1[src] + d1[dst] + ea[e]@Wa1_ea + ba1
    if (tid < EE) {
        float a = ba1[0];
        #pragma unroll
        for (int k = 0; k < 16; k++) a += sh_ea[tid][k] * Wa1[2 * DD1 + k];
        sh_elog[tid] = a;
    }
    if (tid < 176) { // 22 rows x 8 lanes
        int g = tid >> 3, jj = tid & 7;
        int n = (g < NN) ? g : (g - NN);
        const float* wa = (g < NN) ? Wa1 : (Wa1 + DD1);
        float s = 0.f;
        for (int k = jj; k < DD1; k += 8) s += sh_h1[n][k] * wa[k];
        red[tid] = s;
    }
    __syncthreads();
    if (tid < 22) {
        float s = 0.f;
        #pragma unroll
        for (int j2 = 0; j2 < 8; j2++) s += red[tid * 8 + j2];
        if (tid < NN) sh_s1[tid] = s; else sh_d1[tid - NN] = s;
    }
    __syncthreads();
    if (tid < EE) sh_logit[tid] = sh_s1[s_src[tid]] + sh_d1[s_dst[tid]] + sh_elog[tid];
    __syncthreads();
    // softmax over all E edges
    if (tid < 128) red[tid] = (tid < EE) ? sh_logit[tid] : -3.0e38f;
    __syncthreads();
    for (int s = 64; s > 0; s >>= 1) {
        if (tid < s) red[tid] = fmaxf(red[tid], red[tid + s]);
        __syncthreads();
    }
    if (tid == 0) sredv[0] = red[0];
    __syncthreads();
    if (tid < 128) {
        float v = (tid < EE) ? expf(sh_logit[tid] - sredv[0]) : 0.f;
        if (tid < EE) sh_alpha[tid] = v;
        red[tid] = v;
    }
    __syncthreads();
    for (int s = 64; s > 0; s >>= 1) {
        if (tid < s) red[tid] += red[tid + s];
        __syncthreads();
    }
    if (tid == 0) sredv[1] = 1.f / red[0];
    __syncthreads();
    if (tid < EE) sh_alpha[tid] *= sredv[1];
    __syncthreads();
    // aggregate: x1 = relu(segment_sum(alpha * h1[src], dst))
    for (int i = tid; i < NN * DD1; i += 256) {
        int n = i >> 8, d = i & 255;
        float a = 0.f;
        for (int p = deg_start[n]; p < deg_start[n + 1]; p++) {
            int e = e_by_dst[p];
            a += sh_alpha[e] * sh_h1[s_src[e]][d];
        }
        sh_x[n][d] = fmaxf(a, 0.f);
    }
    __syncthreads();

    // ======================= GAT layer 2 ====================================
    { // linear: sh_h1 = sh_x @ Wg2 + bg2  (in-dim 256)
        const int j = tid;
        float acc[NN];
        #pragma unroll
        for (int n = 0; n < NN; n++) acc[n] = bg2[j];
        for (int k = 0; k < DD1; k += 4) {
            float w0 = Wg2[(k + 0) * DD1 + j], w1 = Wg2[(k + 1) * DD1 + j];
            float w2 = Wg2[(k + 2) * DD1 + j], w3 = Wg2[(k + 3) * DD1 + j];
            #pragma unroll
            for (int n = 0; n < NN; n++) {
                float4 xv = *(const float4*)&sh_x[n][k];
                acc[n] = fmaf(xv.w, w3, fmaf(xv.z, w2, fmaf(xv.y, w1, fmaf(xv.x, w0, acc[n]))));
            }
        }
        #pragma unroll
        for (int n = 0; n < NN; n++) sh_h1[n][j] = acc[n];
    }
    __syncthreads();
    if (tid < EE) {
        float a = ba2[0];
        #pragma unroll
        for (int k = 0; k < 16; k++) a += sh_ea[tid][k] * Wa2[2 * DD1 + k];
        sh_elog[tid] = a;
    }
    if (tid < 176) {
        int g = tid >> 3, jj = tid & 7;
        int n = (g < NN) ? g : (g - NN);
        const float* wa = (g < NN) ? Wa2 : (Wa2 + DD1);
        float s = 0.f;
        for (int k = jj; k < DD1; k += 8) s += sh_h1[n][k] * wa[k];
        red[tid] = s;
    }
    __syncthreads();
    if (tid < 22) {
        float s = 0.f;
        #pragma unroll
        for (int j2 = 0; j2 < 8; j2++) s += red[tid * 8 + j2];
        if (tid < NN) sh_s1[tid] = s; else sh_d1[tid - NN] = s;
    }
    __syncthreads();
    if (tid < EE) sh_logit[tid] = sh_s1[s_src[tid]] + sh_d1[s_dst[tid]] + sh_elog[tid];
    __syncthreads();
    if (tid < 128) red[tid] = (tid < EE) ? sh_logit[tid] : -3.0e38f;
    __syncthreads();
    for (int s = 64; s > 0; s >>= 1) {
        if (tid < s) red[tid] = fmaxf(red[tid], red[tid + s]);
        __syncthreads();
    }
    if (tid == 0) sredv[0] = red[0];
    __syncthreads();
    if (tid < 128) {
        float v = (tid < EE) ? expf(sh_logit[tid] - sredv[0]) : 0.f;
        if (tid < EE) sh_alpha[tid] = v;
        red[tid] = v;
    }
    __syncthreads();
    for (int s = 64; s > 0; s >>= 1) {
        if (tid < s) red[tid] += red[tid + s];
        __syncthreads();
    }
    if (tid == 0) sredv[1] = 1.f / red[0];
    __syncthreads();
    if (tid < EE) sh_alpha[tid] *= sredv[1];
    __syncthreads();
    for (int i = tid; i < NN * DD1; i += 256) {
        int n = i >> 8, d = i & 255;
        float a = 0.f;
        for (int p = deg_start[n]; p < deg_start[n + 1]; p++) {
            int e = e_by_dst[p];
            a += sh_alpha[e] * sh_h1[s_src[e]][d];
        }
        sh_x[n][d] = fmaxf(a, 0.f);  // x2 (pre-LN)
    }
    __syncthreads();

    // ---- LayerNorm over last dim ------------------------------------------
    if (tid < 176) { // 11 rows x 16 lanes
        int n = tid >> 4, jj = tid & 15;
        float s = 0.f, q = 0.f;
        for (int k = jj; k < DD1; k += 16) {
            float v = sh_x[n][k];
            s += v; q += v * v;
        }
        red[tid] = s; red[176 + tid] = q;
    }
    __syncthreads();
    if (tid < NN) {
        float s = 0.f, q = 0.f;
        #pragma unroll
        for (int j2 = 0; j2 < 16; j2++) { s += red[tid * 16 + j2]; q += red[176 + tid * 16 + j2]; }
        float mu = s * (1.f / 256.f);
        float var = q * (1.f / 256.f) - mu * mu;
        sh_mu[tid] = mu;
        sh_rs[tid] = 1.f / sqrtf(var + 1e-5f);
    }
    __syncthreads();
    for (int i = tid; i < NN * DD1; i += 256) {
        int n = i >> 8, d = i & 255;
        sh_x[n][d] = ln_g[d] * (sh_x[n][d] - sh_mu[n]) * sh_rs[n] + ln_b[d];
    }
    __syncthreads();

    // ---- gi = x2ln @ W_ih + b_ih  (11 x 768), thread owns 3 columns --------
    #pragma unroll
    for (int c = 0; c < 3; c++) {
        const int j = tid + c * 256;
        float acc[NN];
        float bj = b_ih[j];
        #pragma unroll
        for (int n = 0; n < NN; n++) acc[n] = bj;
        for (int k = 0; k < HIDD; k += 4) {
            float w0 = W_ih[(size_t)(k + 0) * G3 + j], w1 = W_ih[(size_t)(k + 1) * G3 + j];
            float w2 = W_ih[(size_t)(k + 2) * G3 + j], w3 = W_ih[(size_t)(k + 3) * G3 + j];
            #pragma unroll
            for (int n = 0; n < NN; n++) {
                float4 xv = *(const float4*)&sh_x[n][k];
                acc[n] = fmaf(xv.w, w3, fmaf(xv.z, w2, fmaf(xv.y, w1, fmaf(xv.x, w0, acc[n]))));
            }
        }
        #pragma unroll
        for (int n = 0; n < NN; n++)
            gi_out[(size_t)t * NN * G3 + n * G3 + j] = acc[n];
    }

    // ---- evc = ev @ Wf[256:288,:] + bf  (shared across nodes) --------------
    {
        float a = bf_[tid];
        #pragma unroll
        for (int k = 0; k < EEDD; k++) a += sev[k] * Wf[(size_t)(HIDD + k) * HIDD + tid];
        evc_out[(size_t)t * HIDD + tid] = a;
    }
}

// ---------------------------------------------------------------------------
// Kernel B: sequential GRU scan. Single block (1 CU), thread owns one of the
// 768 gh columns. h kept in LDS; gi prefetched into registers per step.
// ---------------------------------------------------------------------------
__global__ __launch_bounds__(768) void scan_kernel(
    const float* __restrict__ gi, const float* __restrict__ W_hh,
    const float* __restrict__ b_hh, const float* __restrict__ hx,
    float* __restrict__ h_all)
{
    const int tid = threadIdx.x;
    __shared__ __align__(16) float hs[NN][HIDD];
    __shared__ float gh[NN][G3];

    for (int i = tid; i < NN * HIDD; i += 768) hs[i >> 8][i & 255] = hx[i];
    const float bh = b_hh[tid];
    __syncthreads();

    for (int t = 0; t < TT; t++) {
        // prefetch gi_t (independent of gh compute below)
        float pir[4], piz[4], pin[4];
        #pragma unroll
        for (int q = 0; q < 4; q++) {
            int i = tid + q * 768;
            if (i < NN * HIDD) {
                const float* g = gi + (size_t)t * NN * G3 + (size_t)(i >> 8) * G3;
                int u = i & 255;
                pir[q] = g[u]; piz[q] = g[HIDD + u]; pin[q] = g[2 * HIDD + u];
            }
        }
        // gh = hs @ W_hh + b_hh (column tid)
        float acc[NN];
        #pragma unroll
        for (int n = 0; n < NN; n++) acc[n] = bh;
        for (int k = 0; k < HIDD; k += 4) {
            float w0 = W_hh[(size_t)(k + 0) * G3 + tid];
            float w1 = W_hh[(size_t)(k + 1) * G3 + tid];
            float w2 = W_hh[(size_t)(k + 2) * G3 + tid];
            float w3 = W_hh[(size_t)(k + 3) * G3 + tid];
            #pragma unroll
            for (int n = 0; n < NN; n++) {
                float4 hv = *(const float4*)&hs[n][k];
                acc[n] = fmaf(hv.w, w3, fmaf(hv.z, w2, fmaf(hv.y, w1, fmaf(hv.x, w0, acc[n]))));
            }
        }
        #pragma unroll
        for (int n = 0; n < NN; n++) gh[n][tid] = acc[n];
        __syncthreads();
        // gates + state update
        #pragma unroll
        for (int q = 0; q < 4; q++) {
            int i = tid + q * 768;
            if (i < NN * HIDD) {
                int n = i >> 8, u = i & 255;
                float r = 1.f / (1.f + expf(-(pir[q] + gh[n][u])));
                float z = 1.f / (1.f + expf(-(piz[q] + gh[n][HIDD + u])));
                float nn = tanhf(pin[q] + r * gh[n][2 * HIDD + u]);
                float hnew = (1.f - z) * nn + z * hs[n][u];
                hs[n][u] = hnew;
                h_all[(size_t)t * NN * HIDD + i] = hnew;
            }
        }
        __syncthreads();
    }
}

// ---------------------------------------------------------------------------
// Kernel C: time-parallel predictor head. One block per timestep.
// ---------------------------------------------------------------------------
__global__ __launch_bounds__(256) void predict_kernel(
    const float* __restrict__ h_all, const float* __restrict__ evc,
    const float* __restrict__ Wf, const float* __restrict__ Wp1,
    const float* __restrict__ bp1, const float* __restrict__ Wp2,
    const float* __restrict__ bp2, float* __restrict__ out)
{
    const int t = blockIdx.x, tid = threadIdx.x;
    __shared__ __align__(16) float sh[NN][HIDD];
    __shared__ __align__(16) float sf[NN][HIDD];
    __shared__ __align__(16) float sp[NN][128];
    __shared__ float red[176];

    for (int i = tid; i < NN * HIDD; i += 256)
        sh[i >> 8][i & 255] = h_all[(size_t)t * NN * HIDD + i];
    __syncthreads();
    { // fused = relu(h @ Wf[0:256,:] + evc_t)
        const int j = tid;
        float acc[NN];
        float e = evc[(size_t)t * HIDD + j];
        #pragma unroll
        for (int n = 0; n < NN; n++) acc[n] = e;
        for (int k = 0; k < HIDD; k += 4) {
            float w0 = Wf[(size_t)(k + 0) * HIDD + j], w1 = Wf[(size_t)(k + 1) * HIDD + j];
            float w2 = Wf[(size_t)(k + 2) * HIDD + j], w3 = Wf[(size_t)(k + 3) * HIDD + j];
            #pragma unroll
            for (int n = 0; n < NN; n++) {
                float4 hv = *(const float4*)&sh[n][k];
                acc[n] = fmaf(hv.w, w3, fmaf(hv.z, w2, fmaf(hv.y, w1, fmaf(hv.x, w0, acc[n]))));
            }
        }
        #pragma unroll
        for (int n = 0; n < NN; n++) sf[n][j] = fmaxf(acc[n], 0.f);
    }
    __syncthreads();
    if (tid < 128) { // p1 = relu(fused @ Wp1 + bp1)
        float acc[NN];
        float b = bp1[tid];
        #pragma unroll
        for (int n = 0; n < NN; n++) acc[n] = b;
        for (int k = 0; k < HIDD; k += 4) {
            float w0 = Wp1[(size_t)(k + 0) * 128 + tid], w1 = Wp1[(size_t)(k + 1) * 128 + tid];
            float w2 = Wp1[(size_t)(k + 2) * 128 + tid], w3 = Wp1[(size_t)(k + 3) * 128 + tid];
            #pragma unroll
            for (int n = 0; n < NN; n++) {
                float4 fv = *(const float4*)&sf[n][k];
                acc[n] = fmaf(fv.w, w3, fmaf(fv.z, w2, fmaf(fv.y, w1, fmaf(fv.x, w0, acc[n]))));
            }
        }
        #pragma unroll
        for (int n = 0; n < NN; n++) sp[n][tid] = fmaxf(acc[n], 0.f);
    }
    __syncthreads();
    if (tid < 176) { // pred = p1 @ Wp2 + bp2
        int n = tid >> 4, jj = tid & 15;
        float s = 0.f;
        for (int k = jj; k < 128; k += 16) s += sp[n][k] * Wp2[k];
        red[tid] = s;
    }
    __syncthreads();
    if (tid < NN) {
        float s = 0.f;
        #pragma unroll
        for (int j2 = 0; j2 < 16; j2++) s += red[tid * 16 + j2];
        out[(size_t)t * NN + tid] = s + bp2[0];
    }
}

// ---------------------------------------------------------------------------
extern "C" void kernel_launch(void* const* d_in, const int* in_sizes, int n_in,
                              void* d_out, int out_size, void* d_ws, size_t ws_size,
                              hipStream_t stream) {
    const float* x_in  = (const float*)d_in[0];
    const float* ea_in = (const float*)d_in[1];
    const float* evs   = (const float*)d_in[2];
    const float* hx    = (const float*)d_in[3];
    const int*   eidx  = (const int*)d_in[4];
    const float* W_np  = (const float*)d_in[5];
    const float* b_np  = (const float*)d_in[6];
    const float* bn_g  = (const float*)d_in[7];
    const float* bn_b  = (const float*)d_in[8];
    const float* We1   = (const float*)d_in[9];
    const float* be1   = (const float*)d_in[10];
    const float* We2   = (const float*)d_in[11];
    const float* be2   = (const float*)d_in[12];
    const float* Wg1   = (const float*)d_in[13];
    const float* bg1   = (const float*)d_in[14];
    const float* Wa1   = (const float*)d_in[15];
    const float* ba1   = (const float*)d_in[16];
    const float* Wg2   = (const float*)d_in[17];
    const float* bg2   = (const float*)d_in[18];
    const float* Wa2   = (const float*)d_in[19];
    const float* ba2   = (const float*)d_in[20];
    const float* ln_g  = (const float*)d_in[21];
    const float* ln_b  = (const float*)d_in[22];
    const float* W_ih  = (const float*)d_in[23];
    const float* W_hh  = (const float*)d_in[24];
    const float* b_ih  = (const float*)d_in[25];
    const float* b_hh  = (const float*)d_in[26];
    const float* Wf    = (const float*)d_in[27];
    const float* bf_   = (const float*)d_in[28];
    const float* Wp1   = (const float*)d_in[29];
    const float* bp1   = (const float*)d_in[30];
    const float* Wp2   = (const float*)d_in[31];
    const float* bp2   = (const float*)d_in[32];

    float* gi   = (float*)d_ws;                       // T*11*768
    float* evc  = gi  + (size_t)TT * NN * G3;         // T*256
    float* hall = evc + (size_t)TT * HIDD;            // T*11*256

    precompute_kernel<<<TT, 256, 0, stream>>>(
        x_in, ea_in, evs, eidx,
        W_np, b_np, bn_g, bn_b, We1, be1, We2, be2,
        Wg1, bg1, Wa1, ba1, Wg2, bg2, Wa2, ba2,
        ln_g, ln_b, W_ih, b_ih, Wf, bf_, gi, evc);

    scan_kernel<<<1, 768, 0, stream>>>(gi, W_hh, b_hh, hx, hall);

    predict_kernel<<<TT, 256, 0, stream>>>(
        hall, evc, Wf, Wp1, bp1, Wp2, bp2, (float*)d_out);
}

// Round 3
// 14182.416 us; speedup vs baseline: 4.0298x; 4.0298x over previous
//
#include <hip/hip_runtime.h>
#include <hip/hip_bf16.h>

#define TT   2048
#define NN   11
#define EE   110
#define NFD  5
#define EFD  4
#define HIDD 256
#define EEDD 32
#define DD1  256
#define G3   768
#define HPAD 264   // bf16 row stride for h in LDS (264*2B = 528B -> bank-friendly, 16B aligned)

typedef __attribute__((ext_vector_type(8))) short short8v;
typedef __attribute__((ext_vector_type(4))) float float4v;

static __device__ inline short f2bf(float f) {
    union { __hip_bfloat16 b; short s; } u; u.b = __float2bfloat16(f); return u.s;
}
static __device__ inline float bf2f(short s) {
    union { short s; __hip_bfloat16 b; } u; u.s = s; return __bfloat162float(u.b);
}
static __device__ inline float sigm_f(float x) {
    return __builtin_amdgcn_rcpf(1.f + __builtin_amdgcn_exp2f(-1.4426950408889634f * x));
}
static __device__ inline float tanh_f(float x) {
    float e = __builtin_amdgcn_exp2f(2.8853900817779268f * x);   // exp(2x)
    return 1.f - 2.f * __builtin_amdgcn_rcpf(e + 1.f);
}
static __device__ inline void gld16(const float* g, float* s) {
    __builtin_amdgcn_global_load_lds((const __attribute__((address_space(1))) void*)g,
                                     (__attribute__((address_space(3))) void*)s, 16, 0, 0);
}

// ---------------------------------------------------------------------------
// Kernel A: time-parallel precompute. One block per timestep t.
// ---------------------------------------------------------------------------
__global__ __launch_bounds__(256) void precompute_kernel(
    const float* __restrict__ x, const float* __restrict__ edge_attr,
    const float* __restrict__ evs, const int* __restrict__ eidx,
    const float* __restrict__ W_np, const float* __restrict__ b_np,
    const float* __restrict__ bn_g, const float* __restrict__ bn_b,
    const float* __restrict__ We1, const float* __restrict__ be1,
    const float* __restrict__ We2, const float* __restrict__ be2,
    const float* __restrict__ Wg1, const float* __restrict__ bg1,
    const float* __restrict__ Wa1, const float* __restrict__ ba1,
    const float* __restrict__ Wg2, const float* __restrict__ bg2,
    const float* __restrict__ Wa2, const float* __restrict__ ba2,
    const float* __restrict__ ln_g, const float* __restrict__ ln_b,
    const float* __restrict__ W_ih, const float* __restrict__ b_ih,
    const float* __restrict__ Wf, const float* __restrict__ bf_,
    float* __restrict__ gi_out, float* __restrict__ evc_out)
{
    const int t   = blockIdx.x;
    const int tid = threadIdx.x;

    __shared__ __align__(16) float sh_h[NN][64];
    __shared__ __align__(16) float sh_e1[EE][32];
    __shared__ __align__(16) float sh_ea[EE][16];
    __shared__ __align__(16) float sh_h1[NN][DD1];
    __shared__ __align__(16) float sh_x[NN][DD1];
    __shared__ float sxt[NN * NFD];
    __shared__ float sev[EEDD];
    __shared__ float seat[EE * EFD];
    __shared__ float red[356];
    __shared__ float sh_s1[NN], sh_d1[NN];
    __shared__ float sh_elog[EE], sh_logit[EE], sh_alpha[EE];
    __shared__ float sh_mu[NN], sh_rs[NN];
    __shared__ float sredv[2];
    __shared__ int s_src[EE], s_dst[EE];
    __shared__ int cnt[NN], deg_start[NN + 1], e_by_dst[EE];

    if (tid < NN * NFD) sxt[tid] = x[(size_t)t * NN * NFD + tid];
    if (tid < EEDD)     sev[tid] = evs[(size_t)t * EEDD + tid];
    for (int i = tid; i < EE * EFD; i += 256)
        seat[i] = edge_attr[(size_t)t * EE * EFD + i];
    if (tid < EE) { s_src[tid] = eidx[tid]; s_dst[tid] = eidx[EE + tid]; }
    if (tid < NN) cnt[tid] = 0;
    __syncthreads();
    if (tid < EE) atomicAdd(&cnt[s_dst[tid]], 1);
    __syncthreads();
    if (tid == 0) {
        int a = 0;
        for (int n = 0; n < NN; n++) { deg_start[n] = a; a += cnt[n]; }
        deg_start[NN] = a;
    }
    __syncthreads();
    if (tid < NN) cnt[tid] = 0;
    __syncthreads();
    if (tid < EE) {
        int d = s_dst[tid];
        int pos = deg_start[d] + atomicAdd(&cnt[d], 1);
        e_by_dst[pos] = tid;
    }

    const float bn_inv = 1.0f / sqrtf(1.0f + 1e-5f);
    __syncthreads();
    for (int i = tid; i < NN * 64; i += 256) {
        int n = i >> 6, d = i & 63;
        float a = b_np[d];
        #pragma unroll
        for (int k = 0; k < NFD; k++) a += sxt[n * NFD + k] * W_np[k * 64 + d];
        a = fmaxf(a, 0.f);
        sh_h[n][d] = bn_g[d] * (a * bn_inv) + bn_b[d];
    }
    __syncthreads();

    for (int i = tid; i < EE * 32; i += 256) {
        int e = i >> 5, d = i & 31;
        float a = be1[d];
        #pragma unroll
        for (int k = 0; k < EFD; k++) a += seat[e * EFD + k] * We1[k * 32 + d];
        sh_e1[e][d] = fmaxf(a, 0.f);
    }
    __syncthreads();
    for (int i = tid; i < EE * 16; i += 256) {
        int e = i >> 4, d = i & 15;
        float a = be2[d];
        #pragma unroll
        for (int k = 0; k < 32; k++) a += sh_e1[e][k] * We2[k * 16 + d];
        sh_ea[e][d] = fmaxf(a, 0.f);
    }
    __syncthreads();

    // ======================= GAT layer 1 ====================================
    {
        const int j = tid;
        float acc[NN];
        #pragma unroll
        for (int n = 0; n < NN; n++) acc[n] = bg1[j];
        for (int k = 0; k < 64; k += 4) {
            float w0 = Wg1[(k + 0) * DD1 + j], w1 = Wg1[(k + 1) * DD1 + j];
            float w2 = Wg1[(k + 2) * DD1 + j], w3 = Wg1[(k + 3) * DD1 + j];
            #pragma unroll
            for (int n = 0; n < NN; n++) {
                float4 hv = *(const float4*)&sh_h[n][k];
                acc[n] = fmaf(hv.w, w3, fmaf(hv.z, w2, fmaf(hv.y, w1, fmaf(hv.x, w0, acc[n]))));
            }
        }
        #pragma unroll
        for (int n = 0; n < NN; n++) sh_h1[n][j] = acc[n];
    }
    __syncthreads();
    if (tid < EE) {
        float a = ba1[0];
        #pragma unroll
        for (int k = 0; k < 16; k++) a += sh_ea[tid][k] * Wa1[2 * DD1 + k];
        sh_elog[tid] = a;
    }
    if (tid < 176) {
        int g = tid >> 3, jj = tid & 7;
        int n = (g < NN) ? g : (g - NN);
        const float* wa = (g < NN) ? Wa1 : (Wa1 + DD1);
        float s = 0.f;
        for (int k = jj; k < DD1; k += 8) s += sh_h1[n][k] * wa[k];
        red[tid] = s;
    }
    __syncthreads();
    if (tid < 22) {
        float s = 0.f;
        #pragma unroll
        for (int j2 = 0; j2 < 8; j2++) s += red[tid * 8 + j2];
        if (tid < NN) sh_s1[tid] = s; else sh_d1[tid - NN] = s;
    }
    __syncthreads();
    if (tid < EE) sh_logit[tid] = sh_s1[s_src[tid]] + sh_d1[s_dst[tid]] + sh_elog[tid];
    __syncthreads();
    if (tid < 128) red[tid] = (tid < EE) ? sh_logit[tid] : -3.0e38f;
    __syncthreads();
    for (int s = 64; s > 0; s >>= 1) {
        if (tid < s) red[tid] = fmaxf(red[tid], red[tid + s]);
        __syncthreads();
    }
    if (tid == 0) sredv[0] = red[0];
    __syncthreads();
    if (tid < 128) {
        float v = (tid < EE) ? expf(sh_logit[tid] - sredv[0]) : 0.f;
        if (tid < EE) sh_alpha[tid] = v;
        red[tid] = v;
    }
    __syncthreads();
    for (int s = 64; s > 0; s >>= 1) {
        if (tid < s) red[tid] += red[tid + s];
        __syncthreads();
    }
    if (tid == 0) sredv[1] = 1.f / red[0];
    __syncthreads();
    if (tid < EE) sh_alpha[tid] *= sredv[1];
    __syncthreads();
    for (int i = tid; i < NN * DD1; i += 256) {
        int n = i >> 8, d = i & 255;
        float a = 0.f;
        for (int p = deg_start[n]; p < deg_start[n + 1]; p++) {
            int e = e_by_dst[p];
            a += sh_alpha[e] * sh_h1[s_src[e]][d];
        }
        sh_x[n][d] = fmaxf(a, 0.f);
    }
    __syncthreads();

    // ======================= GAT layer 2 ====================================
    {
        const int j = tid;
        float acc[NN];
        #pragma unroll
        for (int n = 0; n < NN; n++) acc[n] = bg2[j];
        for (int k = 0; k < DD1; k += 4) {
            float w0 = Wg2[(k + 0) * DD1 + j], w1 = Wg2[(k + 1) * DD1 + j];
            float w2 = Wg2[(k + 2) * DD1 + j], w3 = Wg2[(k + 3) * DD1 + j];
            #pragma unroll
            for (int n = 0; n < NN; n++) {
                float4 xv = *(const float4*)&sh_x[n][k];
                acc[n] = fmaf(xv.w, w3, fmaf(xv.z, w2, fmaf(xv.y, w1, fmaf(xv.x, w0, acc[n]))));
            }
        }
        #pragma unroll
        for (int n = 0; n < NN; n++) sh_h1[n][j] = acc[n];
    }
    __syncthreads();
    if (tid < EE) {
        float a = ba2[0];
        #pragma unroll
        for (int k = 0; k < 16; k++) a += sh_ea[tid][k] * Wa2[2 * DD1 + k];
        sh_elog[tid] = a;
    }
    if (tid < 176) {
        int g = tid >> 3, jj = tid & 7;
        int n = (g < NN) ? g : (g - NN);
        const float* wa = (g < NN) ? Wa2 : (Wa2 + DD1);
        float s = 0.f;
        for (int k = jj; k < DD1; k += 8) s += sh_h1[n][k] * wa[k];
        red[tid] = s;
    }
    __syncthreads();
    if (tid < 22) {
        float s = 0.f;
        #pragma unroll
        for (int j2 = 0; j2 < 8; j2++) s += red[tid * 8 + j2];
        if (tid < NN) sh_s1[tid] = s; else sh_d1[tid - NN] = s;
    }
    __syncthreads();
    if (tid < EE) sh_logit[tid] = sh_s1[s_src[tid]] + sh_d1[s_dst[tid]] + sh_elog[tid];
    __syncthreads();
    if (tid < 128) red[tid] = (tid < EE) ? sh_logit[tid] : -3.0e38f;
    __syncthreads();
    for (int s = 64; s > 0; s >>= 1) {
        if (tid < s) red[tid] = fmaxf(red[tid], red[tid + s]);
        __syncthreads();
    }
    if (tid == 0) sredv[0] = red[0];
    __syncthreads();
    if (tid < 128) {
        float v = (tid < EE) ? expf(sh_logit[tid] - sredv[0]) : 0.f;
        if (tid < EE) sh_alpha[tid] = v;
        red[tid] = v;
    }
    __syncthreads();
    for (int s = 64; s > 0; s >>= 1) {
        if (tid < s) red[tid] += red[tid + s];
        __syncthreads();
    }
    if (tid == 0) sredv[1] = 1.f / red[0];
    __syncthreads();
    if (tid < EE) sh_alpha[tid] *= sredv[1];
    __syncthreads();
    for (int i = tid; i < NN * DD1; i += 256) {
        int n = i >> 8, d = i & 255;
        float a = 0.f;
        for (int p = deg_start[n]; p < deg_start[n + 1]; p++) {
            int e = e_by_dst[p];
            a += sh_alpha[e] * sh_h1[s_src[e]][d];
        }
        sh_x[n][d] = fmaxf(a, 0.f);
    }
    __syncthreads();

    // ---- LayerNorm ---------------------------------------------------------
    if (tid < 176) {
        int n = tid >> 4, jj = tid & 15;
        float s = 0.f, q = 0.f;
        for (int k = jj; k < DD1; k += 16) {
            float v = sh_x[n][k];
            s += v; q += v * v;
        }
        red[tid] = s; red[176 + tid] = q;
    }
    __syncthreads();
    if (tid < NN) {
        float s = 0.f, q = 0.f;
        #pragma unroll
        for (int j2 = 0; j2 < 16; j2++) { s += red[tid * 16 + j2]; q += red[176 + tid * 16 + j2]; }
        float mu = s * (1.f / 256.f);
        float var = q * (1.f / 256.f) - mu * mu;
        sh_mu[tid] = mu;
        sh_rs[tid] = 1.f / sqrtf(var + 1e-5f);
    }
    __syncthreads();
    for (int i = tid; i < NN * DD1; i += 256) {
        int n = i >> 8, d = i & 255;
        sh_x[n][d] = ln_g[d] * (sh_x[n][d] - sh_mu[n]) * sh_rs[n] + ln_b[d];
    }
    __syncthreads();

    // ---- gi = x2ln @ W_ih + b_ih -------------------------------------------
    #pragma unroll
    for (int c = 0; c < 3; c++) {
        const int j = tid + c * 256;
        float acc[NN];
        float bj = b_ih[j];
        #pragma unroll
        for (int n = 0; n < NN; n++) acc[n] = bj;
        for (int k = 0; k < HIDD; k += 4) {
            float w0 = W_ih[(size_t)(k + 0) * G3 + j], w1 = W_ih[(size_t)(k + 1) * G3 + j];
            float w2 = W_ih[(size_t)(k + 2) * G3 + j], w3 = W_ih[(size_t)(k + 3) * G3 + j];
            #pragma unroll
            for (int n = 0; n < NN; n++) {
                float4 xv = *(const float4*)&sh_x[n][k];
                acc[n] = fmaf(xv.w, w3, fmaf(xv.z, w2, fmaf(xv.y, w1, fmaf(xv.x, w0, acc[n]))));
            }
        }
        #pragma unroll
        for (int n = 0; n < NN; n++)
            gi_out[(size_t)t * NN * G3 + n * G3 + j] = acc[n];
    }

    {
        float a = bf_[tid];
        #pragma unroll
        for (int k = 0; k < EEDD; k++) a += sev[k] * Wf[(size_t)(HIDD + k) * HIDD + tid];
        evc_out[(size_t)t * HIDD + tid] = a;
    }
}

// ---------------------------------------------------------------------------
// Kernel B: MFMA GRU scan. 1 block, 4 waves (1 wave/SIMD, ~490 VGPR).
// W_hh held as bf16 B-fragments in registers for ALL 2048 steps.
// h carried in fp32 registers (C-layout-fixed), split hi/lo bf16 for MFMA A.
// Wave w owns h-columns [64w, 64w+64) => its 12 B-frags cover matching
// r/z/n gh columns => gates are pure in-register.
// ---------------------------------------------------------------------------
__global__ __launch_bounds__(256, 1) void scan_mfma_kernel(
    const float* __restrict__ gi, const float* __restrict__ W_hh,
    const float* __restrict__ b_hh, const float* __restrict__ hx,
    float* __restrict__ h_all)
{
    const int tid = threadIdx.x;
    const int w  = tid >> 6;       // wave 0..3
    const int l  = tid & 63;       // lane
    const int lc = l & 15;         // col within fragment
    const int lg = l >> 4;         // k/row group

    __shared__ short sh_hi[16 * HPAD];
    __shared__ short sh_lo[16 * HPAD];
    __shared__ float sgi[2 * NN * G3];   // double-buffered gi(t); also W staging scratch

    // zero h LDS (incl. pad rows 11..15 used by MFMA A)
    for (int i = tid; i < 16 * HPAD; i += 256) { sh_hi[i] = 0; sh_lo[i] = 0; }

    // ---- one-time: load W_hh into bf16 B-fragments (coalesced via LDS) -----
    // frag nf = g*4+f covers cols colbase = g*256 + w*64 + f*16 .. +16
    short8v wf[96];                // [kk*12 + nf], 384 VGPRs
    #pragma unroll
    for (int blk = 0; blk < 16; blk++) {
        __syncthreads();
        // stage W rows [blk*16, blk*16+16) coalesced
        for (int i = tid; i < 16 * G3; i += 256)
            sgi[i] = W_hh[(size_t)(blk * 16) * G3 + i];
        __syncthreads();
        const int kk = blk >> 1, half = blk & 1;
        if ((lg >> 1) == half) {
            const int rbase = lg * 8 - half * 16;   // 0 or 8
            #pragma unroll
            for (int nf = 0; nf < 12; nf++) {
                const int col = ((nf >> 2) << 8) + w * 64 + ((nf & 3) << 4) + lc;
                short8v v;
                #pragma unroll
                for (int j = 0; j < 8; j++)
                    v[j] = f2bf(sgi[(rbase + j) * G3 + col]);
                wf[kk * 12 + nf] = v;
            }
        }
    }

    // ---- per-frag b_hh bias + initial h ------------------------------------
    float bias[12];
    #pragma unroll
    for (int nf = 0; nf < 12; nf++)
        bias[nf] = b_hh[((nf >> 2) << 8) + w * 64 + ((nf & 3) << 4) + lc];

    float hreg[16];   // [f*4+q]: h at (n = lg*4+q, u = w*64 + f*16 + lc)
    #pragma unroll
    for (int f = 0; f < 4; f++) {
        const int u = w * 64 + f * 16 + lc;
        #pragma unroll
        for (int q = 0; q < 4; q++) {
            const int n = lg * 4 + q;
            float h0 = (n < NN) ? hx[n * HIDD + u] : 0.f;
            hreg[f * 4 + q] = h0;
            short hi = f2bf(h0);
            sh_hi[n * HPAD + u] = hi;
            sh_lo[n * HPAD + u] = f2bf(h0 - bf2f(hi));
        }
    }
    __syncthreads();   // W staging reads done; h LDS ready

    // prologue: prefetch gi(0) into buffer 0 (33 x 1KB chunks, split by wave)
    for (int c = w; c < 33; c += 4)
        gld16(gi + c * 256 + l * 4, sgi + c * 256);

    for (int t = 0; t < TT; t++) {
        const float* gicur = sgi + (t & 1) * (NN * G3);

        // ---- phase 1a: prefetch gi(t+1) into other buffer ------------------
        if (t + 1 < TT) {
            const float* gsrc = gi + (size_t)(t + 1) * (NN * G3);
            float* ldst = sgi + ((t + 1) & 1) * (NN * G3);
            for (int c = w; c < 33; c += 4)
                gld16(gsrc + c * 256 + l * 4, ldst + c * 256);
        }

        // ---- phase 1b: gh = (h_hi + h_lo) @ W + b_hh via MFMA --------------
        float4v acc[12];
        #pragma unroll
        for (int nf = 0; nf < 12; nf++)
            acc[nf] = (float4v){bias[nf], bias[nf], bias[nf], bias[nf]};
        #pragma unroll
        for (int kk = 0; kk < 8; kk++) {
            const int ko = kk * 32 + lg * 8;
            short8v ahi = *(const short8v*)&sh_hi[lc * HPAD + ko];
            short8v alo = *(const short8v*)&sh_lo[lc * HPAD + ko];
            #pragma unroll
            for (int nf = 0; nf < 12; nf++) {
                acc[nf] = __builtin_amdgcn_mfma_f32_16x16x32_bf16(ahi, wf[kk * 12 + nf], acc[nf], 0, 0, 0);
                acc[nf] = __builtin_amdgcn_mfma_f32_16x16x32_bf16(alo, wf[kk * 12 + nf], acc[nf], 0, 0, 0);
            }
        }
        __syncthreads();   // all h reads done; gi(t) DMA drained (vmcnt0 at barrier)

        // ---- phase 2: gates in registers, update h -------------------------
        // acc[0*4+f]=r-gate, acc[1*4+f]=z-gate, acc[2*4+f]=n-gate (all + b_hh)
        #pragma unroll
        for (int f = 0; f < 4; f++) {
            const int u = w * 64 + f * 16 + lc;
            #pragma unroll
            for (int q = 0; q < 4; q++) {
                const int n = lg * 4 + q;
                const int ncl = (n < NN) ? n : 0;
                float gir = gicur[ncl * G3 + u];
                float giz = gicur[ncl * G3 + 256 + u];
                float gin = gicur[ncl * G3 + 512 + u];
                float r  = sigm_f(gir + acc[f][q]);
                float z  = sigm_f(giz + acc[4 + f][q]);
                float nn_ = tanh_f(gin + r * acc[8 + f][q]);
                float hold = hreg[f * 4 + q];
                float hnew = z * hold + (1.f - z) * nn_;
                hreg[f * 4 + q] = hnew;
                if (n < NN) {
                    short hi = f2bf(hnew);
                    sh_hi[n * HPAD + u] = hi;
                    sh_lo[n * HPAD + u] = f2bf(hnew - bf2f(hi));
                    h_all[(size_t)t * (NN * HIDD) + n * HIDD + u] = hnew;
                }
            }
        }
        __syncthreads();   // h writes visible before next step's reads
    }
}

// ---------------------------------------------------------------------------
// Kernel C: time-parallel predictor head. One block per timestep.
// ---------------------------------------------------------------------------
__global__ __launch_bounds__(256) void predict_kernel(
    const float* __restrict__ h_all, const float* __restrict__ evc,
    const float* __restrict__ Wf, const float* __restrict__ Wp1,
    const float* __restrict__ bp1, const float* __restrict__ Wp2,
    const float* __restrict__ bp2, float* __restrict__ out)
{
    const int t = blockIdx.x, tid = threadIdx.x;
    __shared__ __align__(16) float sh[NN][HIDD];
    __shared__ __align__(16) float sf[NN][HIDD];
    __shared__ __align__(16) float sp[NN][128];
    __shared__ float red[176];

    for (int i = tid; i < NN * HIDD; i += 256)
        sh[i >> 8][i & 255] = h_all[(size_t)t * NN * HIDD + i];
    __syncthreads();
    {
        const int j = tid;
        float acc[NN];
        float e = evc[(size_t)t * HIDD + j];
        #pragma unroll
        for (int n = 0; n < NN; n++) acc[n] = e;
        for (int k = 0; k < HIDD; k += 4) {
            float w0 = Wf[(size_t)(k + 0) * HIDD + j], w1 = Wf[(size_t)(k + 1) * HIDD + j];
            float w2 = Wf[(size_t)(k + 2) * HIDD + j], w3 = Wf[(size_t)(k + 3) * HIDD + j];
            #pragma unroll
            for (int n = 0; n < NN; n++) {
                float4 hv = *(const float4*)&sh[n][k];
                acc[n] = fmaf(hv.w, w3, fmaf(hv.z, w2, fmaf(hv.y, w1, fmaf(hv.x, w0, acc[n]))));
            }
        }
        #pragma unroll
        for (int n = 0; n < NN; n++) sf[n][j] = fmaxf(acc[n], 0.f);
    }
    __syncthreads();
    if (tid < 128) {
        float acc[NN];
        float b = bp1[tid];
        #pragma unroll
        for (int n = 0; n < NN; n++) acc[n] = b;
        for (int k = 0; k < HIDD; k += 4) {
            float w0 = Wp1[(size_t)(k + 0) * 128 + tid], w1 = Wp1[(size_t)(k + 1) * 128 + tid];
            float w2 = Wp1[(size_t)(k + 2) * 128 + tid], w3 = Wp1[(size_t)(k + 3) * 128 + tid];
            #pragma unroll
            for (int n = 0; n < NN; n++) {
                float4 fv = *(const float4*)&sf[n][k];
                acc[n] = fmaf(fv.w, w3, fmaf(fv.z, w2, fmaf(fv.y, w1, fmaf(fv.x, w0, acc[n]))));
            }
        }
        #pragma unroll
        for (int n = 0; n < NN; n++) sp[n][tid] = fmaxf(acc[n], 0.f);
    }
    __syncthreads();
    if (tid < 176) {
        int n = tid >> 4, jj = tid & 15;
        float s = 0.f;
        for (int k = jj; k < 128; k += 16) s += sp[n][k] * Wp2[k];
        red[tid] = s;
    }
    __syncthreads();
    if (tid < NN) {
        float s = 0.f;
        #pragma unroll
        for (int j2 = 0; j2 < 16; j2++) s += red[tid * 16 + j2];
        out[(size_t)t * NN + tid] = s + bp2[0];
    }
}

// ---------------------------------------------------------------------------
extern "C" void kernel_launch(void* const* d_in, const int* in_sizes, int n_in,
                              void* d_out, int out_size, void* d_ws, size_t ws_size,
                              hipStream_t stream) {
    const float* x_in  = (const float*)d_in[0];
    const float* ea_in = (const float*)d_in[1];
    const float* evs   = (const float*)d_in[2];
    const float* hx    = (const float*)d_in[3];
    const int*   eidx  = (const int*)d_in[4];
    const float* W_np  = (const float*)d_in[5];
    const float* b_np  = (const float*)d_in[6];
    const float* bn_g  = (const float*)d_in[7];
    const float* bn_b  = (const float*)d_in[8];
    const float* We1   = (const float*)d_in[9];
    const float* be1   = (const float*)d_in[10];
    const float* We2   = (const float*)d_in[11];
    const float* be2   = (const float*)d_in[12];
    const float* Wg1   = (const float*)d_in[13];
    const float* bg1   = (const float*)d_in[14];
    const float* Wa1   = (const float*)d_in[15];
    const float* ba1   = (const float*)d_in[16];
    const float* Wg2   = (const float*)d_in[17];
    const float* bg2   = (const float*)d_in[18];
    const float* Wa2   = (const float*)d_in[19];
    const float* ba2   = (const float*)d_in[20];
    const float* ln_g  = (const float*)d_in[21];
    const float* ln_b  = (const float*)d_in[22];
    const float* W_ih  = (const float*)d_in[23];
    const float* W_hh  = (const float*)d_in[24];
    const float* b_ih  = (const float*)d_in[25];
    const float* b_hh  = (const float*)d_in[26];
    const float* Wf    = (const float*)d_in[27];
    const float* bf_   = (const float*)d_in[28];
    const float* Wp1   = (const float*)d_in[29];
    const float* bp1   = (const float*)d_in[30];
    const float* Wp2   = (const float*)d_in[31];
    const float* bp2   = (const float*)d_in[32];

    float* gi   = (float*)d_ws;                       // T*11*768
    float* evc  = gi  + (size_t)TT * NN * G3;         // T*256
    float* hall = evc + (size_t)TT * HIDD;            // T*11*256

    precompute_kernel<<<TT, 256, 0, stream>>>(
        x_in, ea_in, evs, eidx,
        W_np, b_np, bn_g, bn_b, We1, be1, We2, be2,
        Wg1, bg1, Wa1, ba1, Wg2, bg2, Wa2, ba2,
        ln_g, ln_b, W_ih, b_ih, Wf, bf_, gi, evc);

    scan_mfma_kernel<<<1, 256, 0, stream>>>(gi, W_hh, b_hh, hx, hall);

    predict_kernel<<<TT, 256, 0, stream>>>(
        hall, evc, Wf, Wp1, bp1, Wp2, bp2, (float*)d_out);
}